// Round 8
// baseline (1503.290 us; speedup 1.0000x reference)
//
#include <hip/hip_runtime.h>
#include <math.h>

#define NB 64
#define NC 512
#define NHW 4096
#define NHID 32
#define GRID 256
#define BLK 512
#define CHUNK 4
#define NCHUNKS (NB / CHUNK)      // 16

typedef float f32x4 __attribute__((ext_vector_type(4)));

// Device-scope grid barrier, generation k = 1,2,... cnt/rel zeroed per launch.
// Proven correct in R7.
__device__ __forceinline__ void gbar(unsigned* cnt, unsigned* rel, unsigned k) {
    __threadfence();
    __syncthreads();
    if (threadIdx.x == 0) {
        unsigned old = atomicAdd(cnt, 1u);
        if (old == k * GRID - 1u) {
            __hip_atomic_store(rel, k, __ATOMIC_RELEASE, __HIP_MEMORY_SCOPE_AGENT);
        } else {
            while (__hip_atomic_load(rel, __ATOMIC_ACQUIRE,
                                     __HIP_MEMORY_SCOPE_AGENT) < k) {
                __builtin_amdgcn_s_sleep(2);
            }
        }
    }
    __syncthreads();
}

// 256 blocks x 512 threads, 1 block/CU. Block blk owns channels {2blk, 2blk+1}.
// Per 4-sample chunk: x -> registers (16 f32x4/thread), pool-reduce -> y,
// grid barrier, redundant per-block MLP, scale registers, nt-store.
// x is read from HBM exactly once. CHUNK=4 keeps data VGPRs at 64 (no spill).
__global__ __launch_bounds__(BLK, 2) void fused_kernel(
        const float* __restrict__ x,
        const int* __restrict__ dataset,
        const float* __restrict__ W1,
        const float* __restrict__ W2,
        float* __restrict__ out,
        float* __restrict__ y,
        unsigned* __restrict__ cnt,
        unsigned* __restrict__ rel) {
    const int tid  = threadIdx.x;
    const int blk  = blockIdx.x;
    const int half = tid >> 8;            // which of the block's 2 channels
    const int l256 = tid & 255;
    const int wid  = tid >> 6;            // 0..7
    const int lane = tid & 63;
    const int c0   = blk * 2;

    __shared__ float ysl[CHUNK * NC];     // 8 KiB
    __shared__ float hsl[CHUNK * NHID];
    __shared__ float gsl[CHUNK * 2];
    __shared__ float part[8][CHUNK];
    __shared__ int   esl[CHUNK];

    const f32x4* __restrict__ x4 = reinterpret_cast<const f32x4*>(x);
    f32x4* __restrict__ o4 = reinterpret_cast<f32x4*>(out);

    for (int ci = 0; ci < NCHUNKS; ++ci) {
        const int b0 = ci * CHUNK;

        // ---- load chunk into registers (16 outstanding f32x4 loads) ----
        f32x4 v[CHUNK][4];
#pragma unroll
        for (int s = 0; s < CHUNK; ++s) {
            const int pb = (((b0 + s) * NC + c0 + half) << 10) + l256;
#pragma unroll
            for (int k = 0; k < 4; ++k)
                v[s][k] = x4[pb + (k << 8)];
        }
        // ---- pool ----
#pragma unroll
        for (int s = 0; s < CHUNK; ++s) {
            f32x4 a = v[s][0] + v[s][1] + v[s][2] + v[s][3];
            float t = a.x + a.y + a.z + a.w;
#pragma unroll
            for (int o = 32; o; o >>= 1) t += __shfl_down(t, o, 64);
            if (lane == 0) part[wid][s] = t;
        }
        __syncthreads();
        if (tid < CHUNK * 2) {                   // 8 threads write y
            const int s = tid >> 1, h = tid & 1;
            float t = part[h * 4 + 0][s] + part[h * 4 + 1][s] +
                      part[h * 4 + 2][s] + part[h * 4 + 3][s];
            y[(b0 + s) * NC + c0 + h] = t * (1.0f / NHW);
        }

        // ---- grid barrier: all pools of this chunk complete ----
        gbar(cnt, rel, (unsigned)(ci + 1));

        // ---- gate MLP (redundant per block; agent-scope y reads) ----
        if (tid < CHUNK) esl[tid] = dataset[b0 + tid];
        for (int i = tid; i < CHUNK * NC; i += BLK) {
            const int s = i >> 9, c = i & (NC - 1);
            ysl[i] = __hip_atomic_load(&y[(b0 + s) * NC + c],
                                       __ATOMIC_RELAXED, __HIP_MEMORY_SCOPE_AGENT);
        }
        __syncthreads();
        {
            const int hid = tid >> 4, j = tid & 15;   // 16 lanes per hidden unit
            for (int s = 0; s < CHUNK; ++s) {
                const float* __restrict__ w1row =
                    W1 + ((size_t)esl[s] * NHID + hid) * NC;
                float acc = 0.f;
                for (int c = j; c < NC; c += 16) acc += ysl[s * NC + c] * w1row[c];
#pragma unroll
                for (int o = 8; o; o >>= 1) acc += __shfl_down(acc, o, 16);
                if (j == 0) hsl[s * NHID + hid] = fmaxf(acc, 0.f);
            }
        }
        __syncthreads();
        if (tid < CHUNK * 2) {                   // 8 gates (2 channels x 4 samples)
            const int s = tid >> 1, ch = tid & 1;
            const float* __restrict__ w2row =
                W2 + ((size_t)esl[s] * NC + c0 + ch) * NHID;
            float z = 0.f;
#pragma unroll
            for (int h = 0; h < NHID; ++h) z += hsl[s * NHID + h] * w2row[h];
            gsl[tid] = 1.0f / (1.0f + expf(-z));
        }
        __syncthreads();

        // ---- scale registers + nt-store ----
#pragma unroll
        for (int s = 0; s < CHUNK; ++s) {
            const float g = gsl[s * 2 + half];
            const int pb = (((b0 + s) * NC + c0 + half) << 10) + l256;
#pragma unroll
            for (int k = 0; k < 4; ++k) {
                f32x4 w = v[s][k] * g;
                __builtin_nontemporal_store(w, &o4[pb + (k << 8)]);
            }
        }
    }
}

extern "C" void kernel_launch(void* const* d_in, const int* in_sizes, int n_in,
                              void* d_out, int out_size, void* d_ws, size_t ws_size,
                              hipStream_t stream) {
    const float* x       = (const float*)d_in[0];
    const int*   dataset = (const int*)d_in[1];
    const float* W1      = (const float*)d_in[2];
    const float* W2      = (const float*)d_in[3];
    float* out = (float*)d_out;

    unsigned* cnt = (unsigned*)d_ws;                       // [0]
    unsigned* rel = cnt + 1;                               // [1]
    float*    y   = (float*)((char*)d_ws + 256);           // NB*NC floats

    hipMemsetAsync(d_ws, 0, 256, stream);                  // reset barrier state
    fused_kernel<<<GRID, BLK, 0, stream>>>(x, dataset, W1, W2, out, y, cnt, rel);
}

// Round 9
// 1129.687 us; speedup vs baseline: 1.3307x; 1.3307x over previous
//
#include <hip/hip_runtime.h>
#include <math.h>

#define NB 64
#define NC 512
#define NHW 4096
#define NHID 32
#define GRID 512            // one block per channel
#define BLK 256
#define DSLOT 6             // pipeline depth (register slots)
#define OWNER_LAG 3
#define CONS_LAG 6

typedef float f32x4 __attribute__((ext_vector_type(4)));

// ws layout (bytes):
//   done1 : NB*64 u32   = 16384   @ 0      (64 counters/sample, 8 contributors each)
//   gready: NB u32      = 256     @ 16384
//   pad to 32768
//   y     : NB*NC f32   = 131072  @ 32768
//   gate  : NB*NC f32   = 131072  @ 163840

__global__ __launch_bounds__(BLK, 2) void fused_kernel(
        const float* __restrict__ x,
        const int* __restrict__ dataset,
        const float* __restrict__ W1,
        const float* __restrict__ W2,
        float* __restrict__ out,
        unsigned* __restrict__ done1,
        unsigned* __restrict__ gready,
        float* __restrict__ y,
        float* __restrict__ gate) {
    const int tid  = threadIdx.x;
    const int blk  = blockIdx.x;
    const int wid  = tid >> 6;
    const int lane = tid & 63;
    const int c0   = blk;                 // this block's channel
    const int grp  = blk >> 3;            // done1 group (8 blocks each)

    __shared__ float part[4];
    __shared__ float ysl[NC];
    __shared__ float hsl[NHID];
    __shared__ float gbc;

    const f32x4* __restrict__ x4 = reinterpret_cast<const f32x4*>(x);
    f32x4* __restrict__ o4 = reinterpret_cast<f32x4*>(out);

    f32x4 v[DSLOT][4];

    for (int base = 0; base < NB + CONS_LAG + 2; base += DSLOT) {
#pragma unroll
        for (int u = 0; u < DSLOT; ++u) {
            const int t = base + u;

            // ================= CONSUME sample t-6 (uses slot u) =================
            const int sc = t - CONS_LAG;
            if (sc >= 0 && sc < NB) {
                if (tid == 0) {
                    while (__hip_atomic_load(&gready[sc], __ATOMIC_RELAXED,
                                             __HIP_MEMORY_SCOPE_AGENT) == 0u) {
                        __builtin_amdgcn_s_sleep(1);
                    }
                    gbc = __hip_atomic_load(&gate[sc * NC + c0], __ATOMIC_RELAXED,
                                            __HIP_MEMORY_SCOPE_AGENT);
                }
                __syncthreads();
                const float g = gbc;
                const size_t pb = ((size_t)(sc * NC + c0) << 10) + tid;
#pragma unroll
                for (int k = 0; k < 4; ++k) {
                    f32x4 w = v[u][k] * g;
                    __builtin_nontemporal_store(w, &o4[pb + (size_t)(k << 8)]);
                }
            }

            // ================= OWNER: MLP for sample t-3 =================
            const int sb = t - OWNER_LAG;
            if (sb >= 0 && sb < NB && blk == sb * 8 + (sb & 7)) {
                if (tid < 64) {       // wave0 watches the 64 arrival counters
                    for (;;) {
                        unsigned cv = __hip_atomic_load(&done1[sb * 64 + tid],
                                                        __ATOMIC_RELAXED,
                                                        __HIP_MEMORY_SCOPE_AGENT);
                        if (__all(cv == 8u)) break;
                        __builtin_amdgcn_s_sleep(1);
                    }
                }
                __syncthreads();
                // y row -> LDS (IC-point reads; producers release-ordered)
                ysl[tid] = __hip_atomic_load(&y[sb * NC + tid], __ATOMIC_RELAXED,
                                             __HIP_MEMORY_SCOPE_AGENT);
                ysl[tid + 256] = __hip_atomic_load(&y[sb * NC + tid + 256],
                                                   __ATOMIC_RELAXED,
                                                   __HIP_MEMORY_SCOPE_AGENT);
                const int e = dataset[sb];
                __syncthreads();
                // stage 1: 8 lanes per hidden unit
                {
                    const int hid = tid >> 3, j = tid & 7;
                    const float* __restrict__ w1row =
                        W1 + ((size_t)e * NHID + hid) * NC;
                    float acc = 0.f;
                    for (int c = j; c < NC; c += 8) acc += ysl[c] * w1row[c];
#pragma unroll
                    for (int o = 4; o; o >>= 1) acc += __shfl_down(acc, o, 8);
                    if (j == 0) hsl[hid] = fmaxf(acc, 0.f);
                }
                __syncthreads();
                // stage 2: 2 channels per thread -> gate stores (IC-point)
                const float* __restrict__ w2base = W2 + (size_t)e * NC * NHID;
#pragma unroll
                for (int k = 0; k < 2; ++k) {
                    const int c = tid + k * 256;
                    const float* __restrict__ w2row = w2base + c * NHID;
                    float z = 0.f;
#pragma unroll
                    for (int h = 0; h < NHID; ++h) z += hsl[h] * w2row[h];
                    float gv = 1.0f / (1.0f + expf(-z));
                    __hip_atomic_store(&gate[sb * NC + c], gv, __ATOMIC_RELAXED,
                                       __HIP_MEMORY_SCOPE_AGENT);
                }
                __threadfence();        // drain every thread's gate stores
                __syncthreads();
                if (tid == 0)
                    __hip_atomic_store(&gready[sb], 1u, __ATOMIC_RELEASE,
                                       __HIP_MEMORY_SCOPE_AGENT);
            }

            // ================= PRODUCE sample t (into slot u) =================
            if (t < NB) {
                const size_t pb = ((size_t)(t * NC + c0) << 10) + tid;
#pragma unroll
                for (int k = 0; k < 4; ++k)
                    v[u][k] = x4[pb + (size_t)(k << 8)];

                f32x4 a = v[u][0] + v[u][1] + v[u][2] + v[u][3];
                float s = a.x + a.y + a.z + a.w;
#pragma unroll
                for (int o = 32; o; o >>= 1) s += __shfl_down(s, o, 64);
                __syncthreads();        // protect part[] from prior-iter reader
                if (lane == 0) part[wid] = s;
                __syncthreads();
                if (tid == 0) {
                    float tot = part[0] + part[1] + part[2] + part[3];
                    __hip_atomic_store(&y[t * NC + c0], tot * (1.0f / NHW),
                                       __ATOMIC_RELAXED, __HIP_MEMORY_SCOPE_AGENT);
                    __hip_atomic_fetch_add(&done1[t * 64 + grp], 1u,
                                           __ATOMIC_RELEASE,
                                           __HIP_MEMORY_SCOPE_AGENT);
                }
            }
        }
    }
}

extern "C" void kernel_launch(void* const* d_in, const int* in_sizes, int n_in,
                              void* d_out, int out_size, void* d_ws, size_t ws_size,
                              hipStream_t stream) {
    const float* x       = (const float*)d_in[0];
    const int*   dataset = (const int*)d_in[1];
    const float* W1      = (const float*)d_in[2];
    const float* W2      = (const float*)d_in[3];
    float* out = (float*)d_out;

    unsigned* done1  = (unsigned*)d_ws;
    unsigned* gready = (unsigned*)((char*)d_ws + 16384);
    float*    y      = (float*)((char*)d_ws + 32768);
    float*    gate   = (float*)((char*)d_ws + 163840);

    hipMemsetAsync(d_ws, 0, 32768, stream);   // reset counters + flags
    fused_kernel<<<GRID, BLK, 0, stream>>>(x, dataset, W1, W2, out,
                                           done1, gready, y, gate);
}

// Round 10
// 284.907 us; speedup vs baseline: 5.2764x; 3.9651x over previous
//
#include <hip/hip_runtime.h>
#include <math.h>

#define NB 64
#define NC 512
#define NHW 4096
#define NHID 32
#define NPLANES (NB * NC)          // 32768 planes of 4096 floats
#define SCALE_GRID 2048            // persistent grid-stride blocks (m13-style)

typedef float f32x4 __attribute__((ext_vector_type(4)));

// ---------------- Kernel 1: global average pool ----------------
// Wave-per-plane: each 64-lane wave reduces one 16 KiB plane entirely in
// registers (16 float4/lane), 6-shfl butterfly, no LDS, no barrier.
// Measured ~6.1 TB/s (near read ceiling) — unchanged from R2.
__global__ __launch_bounds__(256) void pool_kernel(const float* __restrict__ x,
                                                   float* __restrict__ y) {
    const int wid   = threadIdx.x >> 6;
    const int lane  = threadIdx.x & 63;
    const int plane = blockIdx.x * 4 + wid;
    const f32x4* __restrict__ xin =
        reinterpret_cast<const f32x4*>(x + (size_t)plane * NHW);

    float s = 0.f;
#pragma unroll
    for (int i = 0; i < 16; ++i) {
        f32x4 v = xin[lane + i * 64];
        s += v.x + v.y + v.z + v.w;
    }
#pragma unroll
    for (int o = 32; o; o >>= 1) s += __shfl_down(s, o, 64);
    if (lane == 0) y[plane] = s * (1.0f / NHW);
}

// ---------------- Kernel 2: routed 2-layer MLP -> sigmoid gate ----------------
// Unchanged from R2 (~3 us).
__global__ __launch_bounds__(256) void gate_kernel(const float* __restrict__ y,
                                                   const int* __restrict__ dataset,
                                                   const float* __restrict__ W1,
                                                   const float* __restrict__ W2,
                                                   float* __restrict__ gate) {
    const int b = blockIdx.x;
    const int tid = threadIdx.x;

    __shared__ float ys[NC];
    __shared__ float hs[NHID];

    ys[tid]       = y[b * NC + tid];
    ys[tid + 256] = y[b * NC + tid + 256];
    const int e = dataset[b];
    __syncthreads();

    const int hid = tid >> 3;
    const int j   = tid & 7;
    const float* __restrict__ w1row = W1 + ((size_t)e * NHID + hid) * NC;
    float acc = 0.f;
    for (int c = j; c < NC; c += 8) acc += ys[c] * w1row[c];
#pragma unroll
    for (int o = 4; o; o >>= 1) acc += __shfl_down(acc, o, 8);
    if (j == 0) hs[hid] = fmaxf(acc, 0.f);
    __syncthreads();

    const float* __restrict__ w2base = W2 + (size_t)e * NC * NHID;
#pragma unroll
    for (int k = 0; k < 2; ++k) {
        const int c = tid + k * 256;
        const float* __restrict__ w2row = w2base + c * NHID;
        float z = 0.f;
#pragma unroll
        for (int hh = 0; hh < NHID; ++hh) z += hs[hh] * w2row[hh];
        gate[b * NC + c] = 1.0f / (1.0f + expf(-z));
    }
}

// ---------------- Kernel 3: out = x * gate[b,c] ----------------
// R2 config (descending traversal, nt stores, 2 planes / step, wave-uniform
// gate) with ONE change: persistent grid-stride blocks (2048) instead of
// 16384 one-shot blocks — m13-copy-style residency, 8 pair-steps per block.
__global__ __launch_bounds__(256) void scale_kernel(const float* __restrict__ x,
                                                    const float* __restrict__ gate,
                                                    float* __restrict__ out) {
    const int npairs = NPLANES / 2;                      // 16384
    const f32x4* __restrict__ xin = reinterpret_cast<const f32x4*>(x);
    f32x4* __restrict__ o4 = reinterpret_cast<f32x4*>(out);
    const int t = threadIdx.x;

    for (int s = blockIdx.x; s < npairs; s += SCALE_GRID) {
        const int pair = npairs - 1 - s;                 // descending
        const int p0 = pair * 2;
        const float g0 = gate[p0];
        const float g1 = gate[p0 + 1];
        const size_t base = (size_t)pair * 2048;         // float4 units

#pragma unroll
        for (int k = 0; k < 4; ++k) {
            const size_t i = base + (size_t)k * 256 + t;
            f32x4 v = xin[i];
            v *= g0;
            __builtin_nontemporal_store(v, &o4[i]);
        }
#pragma unroll
        for (int k = 0; k < 4; ++k) {
            const size_t i = base + 1024 + (size_t)k * 256 + t;
            f32x4 v = xin[i];
            v *= g1;
            __builtin_nontemporal_store(v, &o4[i]);
        }
    }
}

extern "C" void kernel_launch(void* const* d_in, const int* in_sizes, int n_in,
                              void* d_out, int out_size, void* d_ws, size_t ws_size,
                              hipStream_t stream) {
    const float* x       = (const float*)d_in[0];
    const int*   dataset = (const int*)d_in[1];
    const float* W1      = (const float*)d_in[2];
    const float* W2      = (const float*)d_in[3];
    float* out = (float*)d_out;

    float* y    = (float*)d_ws;          // NB*NC floats
    float* gate = y + NB * NC;           // NB*NC floats

    pool_kernel<<<NPLANES / 4, 256, 0, stream>>>(x, y);
    gate_kernel<<<NB, 256, 0, stream>>>(y, dataset, W1, W2, gate);
    scale_kernel<<<SCALE_GRID, 256, 0, stream>>>(x, gate, out);
}